// Round 5
// baseline (103.703 us; speedup 1.0000x reference)
//
#include <hip/hip_runtime.h>
#include <math.h>

#define NUM_CAM   12   // B*N
#define CAM_PER_B 6
#define IMG_H     128
#define IMG_W     352
#define CH        32
#define BEV       200  // BEV_H == BEV_W
#define PIX_PER_B (BEV * BEV)        // 40000
#define PIX_PER_BLOCK 32
#define BLOCKS_PER_B (PIX_PER_B / PIX_PER_BLOCK)  // 1250

typedef float vfloat4 __attribute__((ext_vector_type(4)));

// One block = 32 consecutive BEV pixels (all within one batch b).
// 8 threads per pixel, each handling 4 channels (float4).
// Branch-free: always load (clamped), select val=0 when out-of-range, so all
// 24 corner loads per thread can be in flight simultaneously.
// CORRECTNESS NOTES:
//  - px,py use true IEEE division (matches numpy bit-exactly; R1 passed so).
//  - best starts at -INF: reference max over cameras can be NEGATIVE when all
//    6 cams are valid (0-init clamped those pixels -> 0.625 absmax in R3/R4).
//  - invalid cams contribute exactly 0 (reference's clipped-weight cancellation).
__global__ __launch_bounds__(256) void ipm_kernel(
    const float* __restrict__ imgs,   // (12, 128, 352, 32)
    const float* __restrict__ Ks,     // (12, 4, 4)
    const float* __restrict__ RTs,    // (12, 4, 4)
    float* __restrict__ out)          // (2, 200, 200, 32)
{
    __shared__ float sP[CAM_PER_B][9];  // rows 0..2 of P, cols {0,1,3}

    const int tid = threadIdx.x;
    const int b = blockIdx.x / BLOCKS_PER_B;

    // P = K @ RT (f32, k-ordered accumulation like the reference matmul).
    if (tid < CAM_PER_B * 9) {
        const int cl = tid / 9;         // camera within batch
        const int k  = tid % 9;
        const int r  = k / 3;           // P row 0..2
        const int cc = k % 3;           // 0,1,2 -> cols 0,1,3
        const int col = (cc == 2) ? 3 : cc;
        const float* K  = Ks  + (b * CAM_PER_B + cl) * 16;
        const float* RT = RTs + (b * CAM_PER_B + cl) * 16;
        float acc = 0.0f;
        #pragma unroll
        for (int kk = 0; kk < 4; ++kk)
            acc += K[r * 4 + kk] * RT[kk * 4 + col];
        sP[cl][k] = acc;
    }
    __syncthreads();

    const int px_in_block = tid >> 3;          // 0..31
    const int c4 = (tid & 7) * 4;              // channel offset
    const int pix_id = blockIdx.x * PIX_PER_BLOCK + px_in_block;
    const int rem = pix_id - b * PIX_PER_B;
    const int gy = rem / BEV;
    const int gx = rem - gy * BEV;

    // linspace(-50, 50, 200) computed in f64 then cast to f32 (matches numpy)
    const double step = 100.0 / 199.0;
    const float xf = (float)(-50.0 + (double)gx * step);
    const float yf = (float)(-50.0 + (double)gy * step);

    // ---- Phase 1: projection math + clamped addresses for all 6 cameras ----
    const float* bases[CAM_PER_B];   // corner00 address per camera (clamped)
    float w00[CAM_PER_B], w01[CAM_PER_B], w10[CAM_PER_B], w11[CAM_PER_B];
    bool  valid[CAM_PER_B];

    #pragma unroll
    for (int n = 0; n < CAM_PER_B; ++n) {
        const float p00 = sP[n][0], p01 = sP[n][1], p03 = sP[n][2];
        const float p10 = sP[n][3], p11 = sP[n][4], p13 = sP[n][5];
        const float p20 = sP[n][6], p21 = sP[n][7], p23 = sP[n][8];

        // pc = P @ [yf, xf, 0, 1]; exact IEEE division like the reference
        const float den = (p20 * yf + p21 * xf + p23) + 1e-7f;
        const float px  = (p00 * yf + p01 * xf + p03) / den;
        const float py  = (p10 * yf + p11 * xf + p13) / den;

        const float x0f = floorf(px);
        const float y0f = floorf(py);

        valid[n] = (x0f >= 0.0f) & (x0f <= (float)(IMG_W - 2)) &
                   (y0f >= 0.0f) & (y0f <= (float)(IMG_H - 2));

        // Reference weight formulas (in-range case: x1 = x0+1 unclipped)
        const float wx1 = px - x0f;
        const float wx0 = (x0f + 1.0f) - px;
        const float wy1 = py - y0f;
        const float wy0 = (y0f + 1.0f) - py;
        w00[n] = wx0 * wy0;
        w01[n] = wx0 * wy1;
        w10[n] = wx1 * wy0;
        w11[n] = wx1 * wy1;

        // Clamp indices so loads are always safe (value discarded if !valid)
        const float xc = fminf(fmaxf(x0f, 0.0f), (float)(IMG_W - 2));
        const float yc = fminf(fmaxf(y0f, 0.0f), (float)(IMG_H - 2));
        const int xi = (int)xc;
        const int yi = (int)yc;
        const int cam = b * CAM_PER_B + n;
        bases[n] = imgs + (((size_t)cam * IMG_H + yi) * IMG_W + xi) * CH + c4;
    }

    // ---- Phase 2: branch-free loads + bilinear + running max ----
    float4 best = make_float4(-INFINITY, -INFINITY, -INFINITY, -INFINITY);

    #pragma unroll
    for (int n = 0; n < CAM_PER_B; ++n) {
        const float* base = bases[n];
        const float4 a00 = *(const float4*)(base);
        const float4 a10 = *(const float4*)(base + CH);
        const float4 a01 = *(const float4*)(base + (size_t)IMG_W * CH);
        const float4 a11 = *(const float4*)(base + (size_t)IMG_W * CH + CH);

        const float c00 = w00[n], c01 = w01[n];
        const float c10 = w10[n], c11 = w11[n];

        float4 val;
        // Same summation order as reference: ((t00 + t01) + t10) + t11
        val.x = ((c00 * a00.x + c01 * a01.x) + c10 * a10.x) + c11 * a11.x;
        val.y = ((c00 * a00.y + c01 * a01.y) + c10 * a10.y) + c11 * a11.y;
        val.z = ((c00 * a00.z + c01 * a01.z) + c10 * a10.z) + c11 * a11.z;
        val.w = ((c00 * a00.w + c01 * a01.w) + c10 * a10.w) + c11 * a11.w;

        // Invalid cams contribute exactly 0 (reference's clipped cancellation).
        val.x = valid[n] ? val.x : 0.0f;
        val.y = valid[n] ? val.y : 0.0f;
        val.z = valid[n] ? val.z : 0.0f;
        val.w = valid[n] ? val.w : 0.0f;

        best.x = fmaxf(best.x, val.x);
        best.y = fmaxf(best.y, val.y);
        best.z = fmaxf(best.z, val.z);
        best.w = fmaxf(best.w, val.w);
    }

    // Output is write-once; nontemporal keeps image lines resident in L2.
    vfloat4 bv;
    bv.x = best.x; bv.y = best.y; bv.z = best.z; bv.w = best.w;
    __builtin_nontemporal_store(bv, (vfloat4*)(out + (size_t)pix_id * CH + c4));
}

extern "C" void kernel_launch(void* const* d_in, const int* in_sizes, int n_in,
                              void* d_out, int out_size, void* d_ws, size_t ws_size,
                              hipStream_t stream) {
    const float* images = (const float*)d_in[0];  // (2,6,128,352,32) f32
    const float* Ks     = (const float*)d_in[1];  // (12,4,4) f32
    const float* RTs    = (const float*)d_in[2];  // (12,4,4) f32
    float* out          = (float*)d_out;          // (2,200,200,32) f32

    const int total_blocks = 2 * BLOCKS_PER_B;    // 2500
    ipm_kernel<<<total_blocks, 256, 0, stream>>>(images, Ks, RTs, out);
}

// Round 6
// 99.559 us; speedup vs baseline: 1.0416x; 1.0416x over previous
//
#include <hip/hip_runtime.h>
#include <math.h>

#define NUM_CAM   12   // B*N
#define CAM_PER_B 6
#define IMG_H     128
#define IMG_W     352
#define CH        32
#define BEV       200  // BEV_H == BEV_W
#define PIX_PER_B (BEV * BEV)        // 40000
#define PIX_PER_BLOCK 32
#define BLOCKS_PER_B (PIX_PER_B / PIX_PER_BLOCK)  // 1250

typedef float vfloat4 __attribute__((ext_vector_type(4)));

// One block = 32 consecutive BEV pixels (all within one batch b).
// Phase 1: 192 threads (one per (pixel,camera)) compute projection -> LDS:
//   bilinear weights + corner00 element offset (negative = invalid).
// Phase 2: 8 threads per pixel (float4 of channels each) loop 6 cams reading
//   broadcast LDS params; corner loads only for valid lanes (~1.4/6 cams
//   valid on average -> ~4x fewer gathers than branch-free version).
// CORRECTNESS NOTES (hard-won):
//  - px,py use true IEEE division (rcp-mul flips floor/valid decisions).
//  - best starts at -INF (max over cams can be negative when all cams valid).
//  - invalid cams contribute exactly 0 (reference's clipped-weight cancellation).
//  - linspace in f64 then cast to f32, P=K@RT k-ordered f32, reference
//    summation order ((t00+t01)+t10)+t11.
__global__ __launch_bounds__(256, 6) void ipm_kernel(
    const float* __restrict__ imgs,   // (12, 128, 352, 32)
    const float* __restrict__ Ks,     // (12, 4, 4)
    const float* __restrict__ RTs,    // (12, 4, 4)
    float* __restrict__ out)          // (2, 200, 200, 32)
{
    __shared__ float sw00[CAM_PER_B][PIX_PER_BLOCK];
    __shared__ float sw01[CAM_PER_B][PIX_PER_BLOCK];
    __shared__ float sw10[CAM_PER_B][PIX_PER_BLOCK];
    __shared__ float sw11[CAM_PER_B][PIX_PER_BLOCK];
    __shared__ int   soff[CAM_PER_B][PIX_PER_BLOCK];  // corner00 elem offset; <0 = invalid

    const int tid = threadIdx.x;
    const int b = blockIdx.x / BLOCKS_PER_B;

    // ---- Phase 1: one thread per (camera, pixel) ----
    if (tid < CAM_PER_B * PIX_PER_BLOCK) {
        const int cam = tid >> 5;          // 0..5
        const int pix = tid & 31;          // 0..31
        const int pix_id = blockIdx.x * PIX_PER_BLOCK + pix;
        const int rem = pix_id - b * PIX_PER_B;
        const int gy = rem / BEV;
        const int gx = rem - gy * BEV;

        // linspace(-50,50,200) in f64 then cast to f32 (matches numpy)
        const double step = 100.0 / 199.0;
        const float xf = (float)(-50.0 + (double)gx * step);
        const float yf = (float)(-50.0 + (double)gy * step);

        const int cg = b * CAM_PER_B + cam;      // global camera id
        const float* K  = Ks  + cg * 16;
        const float* RT = RTs + cg * 16;

        // P = K @ RT, rows 0..2, cols {0,1,3}; k-ordered f32 accumulation
        float P[9];
        #pragma unroll
        for (int r = 0; r < 3; ++r) {
            #pragma unroll
            for (int cc = 0; cc < 3; ++cc) {
                const int col = (cc == 2) ? 3 : cc;
                float acc = 0.0f;
                #pragma unroll
                for (int kk = 0; kk < 4; ++kk)
                    acc += K[r * 4 + kk] * RT[kk * 4 + col];
                P[r * 3 + cc] = acc;
            }
        }

        // pc = P @ [yf, xf, 0, 1]; exact IEEE division like the reference
        const float den = (P[6] * yf + P[7] * xf + P[8]) + 1e-7f;
        const float px  = (P[0] * yf + P[1] * xf + P[2]) / den;
        const float py  = (P[3] * yf + P[4] * xf + P[5]) / den;

        const float x0f = floorf(px);
        const float y0f = floorf(py);

        const bool valid = (x0f >= 0.0f) & (x0f <= (float)(IMG_W - 2)) &
                           (y0f >= 0.0f) & (y0f <= (float)(IMG_H - 2));

        // Reference weight formulas (in-range: x1 = x0+1 unclipped)
        sw10[cam][pix] = px - x0f;
        sw00[cam][pix] = (x0f + 1.0f) - px;
        sw11[cam][pix] = py - y0f;
        sw01[cam][pix] = (y0f + 1.0f) - py;

        int off = -1;
        if (valid) {
            const int xi = (int)x0f;
            const int yi = (int)y0f;
            off = ((cg * IMG_H + yi) * IMG_W + xi) * CH;
        }
        soff[cam][pix] = off;
    }
    __syncthreads();

    // ---- Phase 2: 8 threads per pixel, 4 channels each ----
    const int pix = tid >> 3;                 // 0..31
    const int c4  = (tid & 7) * 4;            // channel offset
    const int pix_id = blockIdx.x * PIX_PER_BLOCK + pix;

    float4 best = make_float4(-INFINITY, -INFINITY, -INFINITY, -INFINITY);

    #pragma unroll
    for (int n = 0; n < CAM_PER_B; ++n) {
        const int off = soff[n][pix];
        float4 val = make_float4(0.0f, 0.0f, 0.0f, 0.0f);
        if (off >= 0) {
            const float wx0 = sw00[n][pix];
            const float wy0 = sw01[n][pix];
            const float wx1 = sw10[n][pix];
            const float wy1 = sw11[n][pix];

            const float* base = imgs + off + c4;
            const float4 a00 = *(const float4*)(base);
            const float4 a10 = *(const float4*)(base + CH);
            const float4 a01 = *(const float4*)(base + IMG_W * CH);
            const float4 a11 = *(const float4*)(base + IMG_W * CH + CH);

            const float c00 = wx0 * wy0;
            const float c01 = wx0 * wy1;
            const float c10 = wx1 * wy0;
            const float c11 = wx1 * wy1;

            // Reference summation order: ((t00 + t01) + t10) + t11
            val.x = ((c00 * a00.x + c01 * a01.x) + c10 * a10.x) + c11 * a11.x;
            val.y = ((c00 * a00.y + c01 * a01.y) + c10 * a10.y) + c11 * a11.y;
            val.z = ((c00 * a00.z + c01 * a01.z) + c10 * a10.z) + c11 * a11.z;
            val.w = ((c00 * a00.w + c01 * a01.w) + c10 * a10.w) + c11 * a11.w;
        }
        best.x = fmaxf(best.x, val.x);
        best.y = fmaxf(best.y, val.y);
        best.z = fmaxf(best.z, val.z);
        best.w = fmaxf(best.w, val.w);
    }

    // Output is write-once; nontemporal keeps image lines resident in L2.
    vfloat4 bv;
    bv.x = best.x; bv.y = best.y; bv.z = best.z; bv.w = best.w;
    __builtin_nontemporal_store(bv, (vfloat4*)(out + (size_t)pix_id * CH + c4));
}

extern "C" void kernel_launch(void* const* d_in, const int* in_sizes, int n_in,
                              void* d_out, int out_size, void* d_ws, size_t ws_size,
                              hipStream_t stream) {
    const float* images = (const float*)d_in[0];  // (2,6,128,352,32) f32
    const float* Ks     = (const float*)d_in[1];  // (12,4,4) f32
    const float* RTs    = (const float*)d_in[2];  // (12,4,4) f32
    float* out          = (float*)d_out;          // (2,200,200,32) f32

    const int total_blocks = 2 * BLOCKS_PER_B;    // 2500
    ipm_kernel<<<total_blocks, 256, 0, stream>>>(images, Ks, RTs, out);
}